// Round 11
// baseline (417.363 us; speedup 1.0000x reference)
//
#include <hip/hip_runtime.h>
#include <cstdint>

typedef __bf16 bf16;
typedef __bf16 bf16x8 __attribute__((ext_vector_type(8)));
typedef float  f32x4  __attribute__((ext_vector_type(4)));

// direct global->LDS 16B copy: LDS dest is wave-uniform base + lane*16B (HW rule),
// global src is per-lane.
__device__ __forceinline__ void glds16(const void* g, void* l) {
  __builtin_amdgcn_global_load_lds((const __attribute__((address_space(1))) void*)g,
                                   (__attribute__((address_space(3))) void*)l, 16, 0, 0);
}

// ---------------- merged weight prep ----------------
__global__ __launch_bounds__(256) void prep_w(const float* __restrict__ wqkv, const float* __restrict__ wout,
                                              bf16* __restrict__ wqkvT, bf16* __restrict__ woutT) {
  int idx = blockIdx.x * 256 + threadIdx.x;
  if (idx < 98304) {
    int r8 = idx & 63, c = idx >> 6;
    bf16 o[8];
#pragma unroll
    for (int e = 0; e < 8; e++) o[e] = (bf16)wqkv[(long)(r8 * 8 + e) * 1536 + c];
    *(uint4*)(wqkvT + (long)c * 512 + r8 * 8) = *(uint4*)o;
  } else {
    int j = idx - 98304;
    int r8 = j & 63, c = j >> 6;
    bf16 o[8];
#pragma unroll
    for (int e = 0; e < 8; e++) o[e] = (bf16)wout[(long)(r8 * 8 + e) * 512 + c];
    *(uint4*)(woutT + (long)c * 512 + r8 * 8) = *(uint4*)o;
  }
}

// ---------------- LayerNorm: 4 rows per block (one wave per row) ----------------
__global__ __launch_bounds__(256) void ln_kernel(const float* __restrict__ x,
    const float* __restrict__ w, const float* __restrict__ b, bf16* __restrict__ xn) {
  long row = (long)blockIdx.x * 4 + (threadIdx.x >> 6);
  int t = threadIdx.x & 63;
  const float* rp = x + row * 512 + t * 8;
  float4 p0 = *(const float4*)rp;
  float4 p1 = *(const float4*)(rp + 4);
  float vals[8] = {p0.x, p0.y, p0.z, p0.w, p1.x, p1.y, p1.z, p1.w};
  float s = 0.f, s2 = 0.f;
#pragma unroll
  for (int e = 0; e < 8; e++) { s += vals[e]; s2 += vals[e] * vals[e]; }
#pragma unroll
  for (int o = 32; o > 0; o >>= 1) { s += __shfl_xor(s, o); s2 += __shfl_xor(s2, o); }
  float mu = s * (1.f / 512.f);
  float var = s2 * (1.f / 512.f) - mu * mu;
  float rstd = rsqrtf(var + 1e-5f);
  float4 w0 = *(const float4*)(w + t * 8), w1 = *(const float4*)(w + t * 8 + 4);
  float4 b0 = *(const float4*)(b + t * 8), b1 = *(const float4*)(b + t * 8 + 4);
  float wv[8] = {w0.x, w0.y, w0.z, w0.w, w1.x, w1.y, w1.z, w1.w};
  float bv[8] = {b0.x, b0.y, b0.z, b0.w, b1.x, b1.y, b1.z, b1.w};
  bf16 outv[8];
#pragma unroll
  for (int e = 0; e < 8; e++) outv[e] = (bf16)((vals[e] - mu) * rstd * wv[e] + bv[e]);
  *(uint4*)(xn + row * 512 + t * 8) = *(uint4*)outv;
}

enum { MODE_BF16 = 1, MODE_QKV = 2, MODE_RESID = 3, MODE_XZ = 4, MODE_DIAG = 5, MODE_Y0 = 6, MODE_ZY = 7, MODE_BF16T = 8 };

// ---------------- full-K LDS 64x64 GEMM for NS chain: C = alpha * A @ B^T ----------------
// 1-D grid with XCD-aware work remap (confirmed r10: -25 us): id%8 == batch%8 so each
// XCD's private L2 serves only 4 batches (2 MB) instead of all 32 (8 MB thrash).
template <int KDIM, int MODE>
__global__ __launch_bounds__(256) void gemm_ns(
    const bf16* __restrict__ A, const bf16* __restrict__ B, void* __restrict__ C,
    int N, long sA, long sB, long sC, float alpha, float cdiag,
    const float* __restrict__ scal, bf16* __restrict__ aux0, bf16* __restrict__ aux1) {
  constexpr int BM = 64;
  __shared__ __align__(16) bf16 As[BM * KDIM];
  __shared__ __align__(16) bf16 Bs[BM * KDIM];
  const int tid = threadIdx.x, lane = tid & 63, wave = tid >> 6;
  const int quad = lane >> 4, l16 = lane & 15;
  constexpr int LPR = KDIM / 8;
  constexpr int CPW = (BM * KDIM / 512) / 4;
  constexpr int RPC = 64 / LPR;
  // XCD-aware decomposition of the 1-D block id
  const int id = blockIdx.x;
  const int xr = id & 7, g = id >> 3;
  const int batch = xr + 8 * (g >> 4);       // batch%8 == id%8
  const int t16 = g & 15;
  const int bm0 = (t16 >> 2) * BM, bn0 = (t16 & 3) * BM;
  const bf16* Ab = A + (long)batch * sA;
  const bf16* Bb = B + (long)(MODE == MODE_ZY ? (batch & 31) : batch) * sB;

  const int rin = lane / LPR, gr = lane % LPR;
#pragma unroll
  for (int t = 0; t < CPW; t++) {
    int seg = wave * CPW + t;
    int row = seg * RPC + rin;
    int scol = 8 * (gr ^ (row & 7));
    glds16(&Ab[(long)(bm0 + row) * KDIM + scol], &As[seg * 512]);
    glds16(&Bb[(long)(bn0 + row) * KDIM + scol], &Bs[seg * 512]);
  }
  __syncthreads();

  f32x4 zero = {0.f, 0.f, 0.f, 0.f};
  f32x4 acc[4];
#pragma unroll
  for (int j = 0; j < 4; j++) acc[j] = zero;
  const int arow = wave * 16 + l16;
  const int aswz = (l16 & 7) * 8;
#pragma unroll
  for (int ki = 0; ki < KDIM / 32; ki++) {
    int cph = (ki * 32 + quad * 8) ^ aswz;
    bf16x8 af = *(const bf16x8*)&As[arow * KDIM + cph];
    bf16x8 bfr[4];
#pragma unroll
    for (int j = 0; j < 4; j++)
      bfr[j] = *(const bf16x8*)&Bs[(j * 16 + l16) * KDIM + cph];
#pragma unroll
    for (int j = 0; j < 4; j++)
      acc[j] = __builtin_amdgcn_mfma_f32_16x16x32_bf16(af, bfr[j], acc[j], 0, 0, 0);
  }

  const long cb = (long)batch * sC;
  float rscale = 1.f;
  if (MODE == MODE_Y0) rscale = 1.f / (scal[0] * scal[1]);
#pragma unroll
  for (int j = 0; j < 4; j++)
#pragma unroll
    for (int r = 0; r < 4; r++) {
      int row = bm0 + wave * 16 + quad * 4 + r;
      int col = bn0 + j * 16 + l16;
      float v = acc[j][r] * alpha;
      if (MODE == MODE_BF16) {
        ((bf16*)C)[cb + (long)row * N + col] = (bf16)v;
      } else if (MODE == MODE_Y0) {
        long o = cb + (long)row * N + col;
        float vv = v * rscale;
        aux0[o] = (bf16)vv;
        aux1[o] = (bf16)(((row == col) ? cdiag : 0.f) - vv);
      } else if (MODE == MODE_ZY) {
        long o = cb + (long)row * N + col;
        ((bf16*)C)[o] = (bf16)v;
        if (batch >= 32) aux1[o - 2097152] = (bf16)(((row == col) ? cdiag : 0.f) - v);
      } else if (MODE == MODE_DIAG) {
        ((bf16*)C)[cb + (long)row * N + col] = (bf16)(((row == col) ? cdiag : 0.f) - v);
      }
    }
}

// ---------------- a2 GEMM with fused row-softmax: a2 = softmax(ql @ kl^T) ----------------
__global__ __launch_bounds__(256) void a2_kernel(const bf16* __restrict__ ql,
    const bf16* __restrict__ kl, bf16* __restrict__ a2h) {
  __shared__ __align__(16) bf16 As[64 * 64];
  __shared__ __align__(16) bf16 Bs[256 * 64];
  const int tid = threadIdx.x, lane = tid & 63, wave = tid >> 6;
  const int quad = lane >> 4, l16 = lane & 15;
  const int bm0 = blockIdx.x * 64, bh = blockIdx.y;
  const bf16* Ab = ql + (long)bh * 16384;
  const bf16* Bb = kl + (long)bh * 16384;

  const int rin = lane >> 3, gr = lane & 7;
#pragma unroll
  for (int t = 0; t < 2; t++) {
    int seg = wave * 2 + t;
    int row = seg * 8 + rin;
    int scol = 8 * (gr ^ (row & 7));
    glds16(&Ab[(long)(bm0 + row) * 64 + scol], &As[seg * 512]);
  }
#pragma unroll
  for (int t = 0; t < 8; t++) {
    int seg = wave * 8 + t;
    int row = seg * 8 + rin;
    int scol = 8 * (gr ^ (row & 7));
    glds16(&Bb[(long)row * 64 + scol], &Bs[seg * 512]);
  }
  __syncthreads();

  f32x4 zero = {0.f, 0.f, 0.f, 0.f};
  f32x4 acc[16];
#pragma unroll
  for (int j = 0; j < 16; j++) acc[j] = zero;
  const int arow = wave * 16 + l16;
  const int aswz = (l16 & 7) * 8;
#pragma unroll
  for (int ki = 0; ki < 2; ki++) {
    int cph = (ki * 32 + quad * 8) ^ aswz;
    bf16x8 af = *(const bf16x8*)&As[arow * 64 + cph];
#pragma unroll
    for (int j = 0; j < 16; j++) {
      bf16x8 bfr = *(const bf16x8*)&Bs[(j * 16 + l16) * 64 + cph];
      acc[j] = __builtin_amdgcn_mfma_f32_16x16x32_bf16(af, bfr, acc[j], 0, 0, 0);
    }
  }

#pragma unroll
  for (int r = 0; r < 4; r++) {
    float vv[16];
    float m = -3.4e38f;
#pragma unroll
    for (int j = 0; j < 16; j++) {
      vv[j] = (float)(bf16)acc[j][r];
      m = fmaxf(m, vv[j]);
    }
#pragma unroll
    for (int o = 1; o < 16; o <<= 1) m = fmaxf(m, __shfl_xor(m, o));
    float s = 0.f;
#pragma unroll
    for (int j = 0; j < 16; j++) { vv[j] = __expf(vv[j] - m); s += vv[j]; }
#pragma unroll
    for (int o = 1; o < 16; o <<= 1) s += __shfl_xor(s, o);
    int row = bm0 + wave * 16 + quad * 4 + r;
    long base = (long)bh * 65536 + (long)row * 256;
#pragma unroll
    for (int j = 0; j < 16; j++)
      a2h[base + j * 16 + l16] = (bf16)(vv[j] / s);
  }
}

// ---------------- BT=true batched MFMA GEMM with glds staging (QKV / RESID) ----------------
template <int BM, int MODE>
__global__ __launch_bounds__(256) void gemm_g(
    const bf16* __restrict__ A, const bf16* __restrict__ B, void* __restrict__ C,
    int N, int K, long sA, long sB, long sC, float alpha, float cdiag,
    const float* __restrict__ resid, const float* __restrict__ bias,
    bf16* __restrict__ aux0, bf16* __restrict__ aux1, bf16* __restrict__ aux2) {
  constexpr int BK = 32, BN = BM;
  __shared__ __align__(16) bf16 As[BM * BK];
  __shared__ __align__(16) bf16 Bs[BN * BK];
  const int tid = threadIdx.x, lane = tid & 63, wave = tid >> 6;
  const int quad = lane >> 4, l16 = lane & 15;
  constexpr int WN = (BN >= 128) ? 2 : 1;
  constexpr int WM = 4 / WN;
  constexpr int TM = BM / (WM * 16), TN = BN / (WN * 16);
  constexpr int ISS = BM / 64;
  const int wm0 = (wave / WN) * (BM / WM);
  const int wn0 = (wave % WN) * (BN / WN);
  const int bm0 = blockIdx.x * BM, bn0 = blockIdx.y * BN;
  const bf16* Ab = A + (long)blockIdx.z * sA;
  const bf16* Bb = B + (long)blockIdx.z * sB;
  const int srow = lane >> 2, scol = (lane & 3) * 8;

  f32x4 zero = {0.f, 0.f, 0.f, 0.f};
  f32x4 acc[TM][TN];
#pragma unroll
  for (int i = 0; i < TM; i++)
#pragma unroll
    for (int j = 0; j < TN; j++) acc[i][j] = zero;

  for (int k0 = 0; k0 < K; k0 += BK) {
#pragma unroll
    for (int t = 0; t < ISS; t++) {
      int seg = wave * ISS + t;
      glds16(&Ab[(long)(bm0 + seg * 16 + srow) * K + k0 + scol], &As[seg * 512]);
      glds16(&Bb[(long)(bn0 + seg * 16 + srow) * K + k0 + scol], &Bs[seg * 512]);
    }
    __syncthreads();
    bf16x8 af[TM], bfr[TN];
#pragma unroll
    for (int i = 0; i < TM; i++)
      af[i] = *(const bf16x8*)&As[(wm0 + i * 16 + l16) * BK + quad * 8];
#pragma unroll
    for (int j = 0; j < TN; j++)
      bfr[j] = *(const bf16x8*)&Bs[(wn0 + j * 16 + l16) * BK + quad * 8];
#pragma unroll
    for (int i = 0; i < TM; i++)
#pragma unroll
      for (int j = 0; j < TN; j++)
        acc[i][j] = __builtin_amdgcn_mfma_f32_16x16x32_bf16(af[i], bfr[j], acc[i][j], 0, 0, 0);
    __syncthreads();
  }

#pragma unroll
  for (int i = 0; i < TM; i++)
#pragma unroll
    for (int j = 0; j < TN; j++)
#pragma unroll
      for (int r = 0; r < 4; r++) {
        int row = bm0 + wm0 + i * 16 + quad * 4 + r;
        int col = bn0 + wn0 + j * 16 + l16;
        float v = acc[i][j][r] * alpha;
        if (MODE == MODE_QKV) {
          int b = row >> 12, n = row & 4095;
          int which = col >> 9, h = (col >> 6) & 7, d = col & 63;
          long o = ((long)(b * 8 + h) * 4096 + n) * 64 + d;
          if (which == 0) aux0[o] = (bf16)(v * 0.125f);
          else if (which == 1) aux1[o] = (bf16)v;
          else aux2[o] = (bf16)v;
        } else {  // MODE_RESID
          long o = (long)row * N + col;
          ((float*)C)[o] = v + bias[col] + resid[o];
        }
      }
}

// ---------------- legacy GEMM (lone BT=false W-gemm, transposed-write epilogue) ----------------
template <int BM, int BN, bool BT, int MODE>
__global__ __launch_bounds__(256) void gemm_k(
    const bf16* __restrict__ A, const bf16* __restrict__ B, void* __restrict__ C,
    int M, int N, int K, long sA, long sB, long sC, float alpha, float cdiag,
    const float* __restrict__ resid, const float* __restrict__ bias,
    bf16* __restrict__ aux0, bf16* __restrict__ aux1, bf16* __restrict__ aux2) {
  constexpr int BK = 32, LDST = 40;
  __shared__ __align__(16) bf16 As[BM * LDST];
  __shared__ __align__(16) bf16 Bs[BN * LDST];
  const int tid = threadIdx.x, lane = tid & 63, wave = tid >> 6;
  const int quad = lane >> 4, l16 = lane & 15;
  constexpr int WN = (BN >= 128) ? 2 : 1;
  constexpr int WM = 4 / WN;
  constexpr int TM = BM / (WM * 16), TN = BN / (WN * 16);
  const int wm0 = (wave / WN) * (BM / WM);
  const int wn0 = (wave % WN) * (BN / WN);
  const int bm0 = blockIdx.x * BM, bn0 = blockIdx.y * BN;
  const bf16* Ab = A + (long)blockIdx.z * sA;
  const bf16* Bb = B + (long)blockIdx.z * sB;

  f32x4 zero = {0.f, 0.f, 0.f, 0.f};
  f32x4 acc[TM][TN];
#pragma unroll
  for (int i = 0; i < TM; i++)
#pragma unroll
    for (int j = 0; j < TN; j++) acc[i][j] = zero;

  for (int k0 = 0; k0 < K; k0 += BK) {
    for (int c = tid; c < BM * 4; c += 256) {
      int r = c >> 2, cv = (c & 3) * 8;
      *(uint4*)&As[r * LDST + cv] = *(const uint4*)&Ab[(long)(bm0 + r) * K + k0 + cv];
    }
    if (BT) {
      for (int c = tid; c < BN * 4; c += 256) {
        int r = c >> 2, cv = (c & 3) * 8;
        *(uint4*)&Bs[r * LDST + cv] = *(const uint4*)&Bb[(long)(bn0 + r) * K + k0 + cv];
      }
    } else {
      for (int c = tid; c < BN * 4; c += 256) {
        int kk = c / (BN / 8), nv = (c % (BN / 8)) * 8;
        uint4 tmp = *(const uint4*)&Bb[(long)(k0 + kk) * N + bn0 + nv];
        const bf16* tv = (const bf16*)&tmp;
#pragma unroll
        for (int e = 0; e < 8; e++) Bs[(nv + e) * LDST + kk] = tv[e];
      }
    }
    __syncthreads();
    bf16x8 af[TM], bfr[TN];
#pragma unroll
    for (int i = 0; i < TM; i++)
      af[i] = *(const bf16x8*)&As[(wm0 + i * 16 + l16) * LDST + quad * 8];
#pragma unroll
    for (int j = 0; j < TN; j++)
      bfr[j] = *(const bf16x8*)&Bs[(wn0 + j * 16 + l16) * LDST + quad * 8];
#pragma unroll
    for (int i = 0; i < TM; i++)
#pragma unroll
      for (int j = 0; j < TN; j++)
        acc[i][j] = __builtin_amdgcn_mfma_f32_16x16x32_bf16(af[i], bfr[j], acc[i][j], 0, 0, 0);
    __syncthreads();
  }

  const long cb = (long)blockIdx.z * sC;
#pragma unroll
  for (int i = 0; i < TM; i++)
#pragma unroll
    for (int j = 0; j < TN; j++)
#pragma unroll
      for (int r = 0; r < 4; r++) {
        int row = bm0 + wm0 + i * 16 + quad * 4 + r;
        int col = bn0 + wn0 + j * 16 + l16;
        float v = acc[i][j][r] * alpha;
        if (MODE == MODE_BF16) {
          ((bf16*)C)[cb + (long)row * N + col] = (bf16)v;
        } else if (MODE == MODE_BF16T) {   // transposed write: C[col][row]
          ((bf16*)C)[cb + (long)col * M + row] = (bf16)v;
        }
      }
}

// ---------------- landmark means ----------------
__global__ __launch_bounds__(256) void lm_kernel(const bf16* __restrict__ q, const bf16* __restrict__ k,
                                                 bf16* __restrict__ ql, bf16* __restrict__ kl) {
  int bh = blockIdx.x, mi = blockIdx.y * 4 + (threadIdx.x >> 6), d = threadIdx.x & 63;
  long base = ((long)bh * 4096 + mi * 16) * 64 + d;
  float sq = 0.f, sk = 0.f;
#pragma unroll
  for (int j = 0; j < 16; j++) { sq += (float)q[base + j * 64]; sk += (float)k[base + j * 64]; }
  long o = ((long)bh * 256 + mi) * 64 + d;
  ql[o] = (bf16)(sq * (1.f / 16.f));
  kl[o] = (bf16)(sk * (1.f / 16.f));
}

// ---------------- pinv scale helpers ----------------
__global__ void init_scal(float* scal) { scal[0] = 1.0f; ((int*)scal)[1] = 0; }

__global__ __launch_bounds__(64) void red_col(const bf16* __restrict__ a2h, float* scal) {
  int bh = blockIdx.x;
  int j = blockIdx.y * 64 + threadIdx.x;
  float s = 0.f;
  const bf16* p = a2h + (long)bh * 65536 + j;
  for (int i = 0; i < 256; i++) s += (float)p[i * 256];
  atomicMax((int*)scal + 1, __float_as_int(s));
}

// z0 = a2^T / c via LDS-tiled 64x64 transpose: coalesced reads AND writes
__global__ __launch_bounds__(256) void z0_k(const bf16* __restrict__ a2h,
                                            const float* __restrict__ scal, bf16* __restrict__ z) {
  int bh = blockIdx.x, ti = blockIdx.y;
  int r0 = (ti >> 2) * 64, c0 = (ti & 3) * 64;
  __shared__ __align__(16) bf16 tile[64][72];
  float inv = 1.f / (scal[0] * scal[1]);
  int tid = threadIdx.x;
  const bf16* src = a2h + (long)bh * 65536;
  bf16* dst = z + (long)bh * 65536;
#pragma unroll
  for (int t = 0; t < 2; t++) {
    int i = tid + t * 256;
    int r = i >> 3, c8 = (i & 7) * 8;
    uint4 pk = *(const uint4*)&src[(long)(r0 + r) * 256 + c0 + c8];
    bf16 tmp[8]; *(uint4*)tmp = pk;
    bf16 sc[8];
#pragma unroll
    for (int e = 0; e < 8; e++) sc[e] = (bf16)((float)tmp[e] * inv);
    *(uint4*)&tile[r][c8] = *(uint4*)sc;
  }
  __syncthreads();
#pragma unroll
  for (int t = 0; t < 2; t++) {
    int i = tid + t * 256;
    int jl = i >> 3, c8 = (i & 7) * 8;
    bf16 o[8];
#pragma unroll
    for (int e = 0; e < 8; e++) o[e] = tile[c8 + e][jl];
    *(uint4*)&dst[(long)(c0 + jl) * 256 + r0 + c8] = *(uint4*)o;
  }
}

// ---------------- F3: fused a3-softmax @ v, 16-way n-split partials ----------------
// Split 8 -> 16: grid 1024 = 4 blocks/CU (was 512 = 2/CU, grid-limited). Per-block
// serial chain halves. vT swizzle + setprio kept (round-6 win).
__global__ __launch_bounds__(256) void f3_partial(const bf16* __restrict__ ql,
    const bf16* __restrict__ k, const bf16* __restrict__ v,
    float* __restrict__ Opart, float* __restrict__ lpart) {
  const int mt = blockIdx.x, ns = blockIdx.y, bh = blockIdx.z;
  const int tid = threadIdx.x, lane = tid & 63, wave = tid >> 6;
  const int quad = lane >> 4, l16 = lane & 15;
  const int wr0 = mt * 128 + wave * 32;
  __shared__ __align__(16) bf16 vT[64][72];
  __shared__ __align__(16) bf16 Pts[4][32][72];

  const bf16* qlb = ql + (long)bh * 16384;
  const bf16* kb  = k + (long)bh * 262144;
  const bf16* vb  = v + (long)bh * 262144;

  bf16x8 aq[2][2];
#pragma unroll
  for (int ti = 0; ti < 2; ti++)
#pragma unroll
    for (int ki = 0; ki < 2; ki++)
      aq[ti][ki] = *(const bf16x8*)&qlb[(wr0 + ti * 16 + l16) * 64 + ki * 32 + quad * 8];

  f32x4 zero = {0.f, 0.f, 0.f, 0.f};
  f32x4 Oacc[2][4];
#pragma unroll
  for (int i = 0; i < 2; i++)
#pragma unroll
    for (int j = 0; j < 4; j++) Oacc[i][j] = zero;
  float lacc[2][4] = {};

  for (int c = 0; c < 4; c++) {
    int n0c = ns * 256 + c * 64;
    __syncthreads();
    for (int i = tid; i < 512; i += 256) {
      int nn = i >> 3, d8 = (i & 7) * 8;
      uint4 pk = *(const uint4*)&vb[(long)(n0c + nn) * 64 + d8];
      const bf16* pv = (const bf16*)&pk;
      int cs = (((nn >> 3) ^ (d8 >> 3)) * 8) + (nn & 7);   // granule-XOR swizzle
#pragma unroll
      for (int e = 0; e < 8; e++) vT[d8 + e][cs] = pv[e];
    }
    __syncthreads();

    f32x4 sacc[2][4];
#pragma unroll
    for (int i = 0; i < 2; i++)
#pragma unroll
      for (int j = 0; j < 4; j++) sacc[i][j] = zero;
#pragma unroll
    for (int ki = 0; ki < 2; ki++) {
      bf16x8 bk[4];
#pragma unroll
      for (int tj = 0; tj < 4; tj++)
        bk[tj] = *(const bf16x8*)&kb[(long)(n0c + tj * 16 + l16) * 64 + ki * 32 + quad * 8];
      __builtin_amdgcn_s_setprio(1);
#pragma unroll
      for (int ti = 0; ti < 2; ti++)
#pragma unroll
        for (int tj = 0; tj < 4; tj++)
          sacc[ti][tj] = __builtin_amdgcn_mfma_f32_16x16x32_bf16(aq[ti][ki], bk[tj], sacc[ti][tj], 0, 0, 0);
      __builtin_amdgcn_s_setprio(0);
    }
#pragma unroll
    for (int ti = 0; ti < 2; ti++)
#pragma unroll
      for (int tj = 0; tj < 4; tj++)
#pragma unroll
        for (int r = 0; r < 4; r++) {
          float e = __expf(sacc[ti][tj][r]);
          lacc[ti][r] += e;
          Pts[wave][ti * 16 + quad * 4 + r][tj * 16 + l16] = (bf16)e;
        }
#pragma unroll
    for (int ki = 0; ki < 2; ki++) {
      bf16x8 ap[2], bv[4];
#pragma unroll
      for (int ti = 0; ti < 2; ti++)
        ap[ti] = *(const bf16x8*)&Pts[wave][ti * 16 + l16][ki * 32 + quad * 8];
#pragma unroll
      for (int tj = 0; tj < 4; tj++) {
        int g = (ki * 4 + quad) ^ ((tj * 2 + (l16 >> 3)) & 7);
        bv[tj] = *(const bf16x8*)&vT[tj * 16 + l16][g * 8];
      }
      __builtin_amdgcn_s_setprio(1);
#pragma unroll
      for (int ti = 0; ti < 2; ti++)
#pragma unroll
        for (int tj = 0; tj < 4; tj++)
          Oacc[ti][tj] = __builtin_amdgcn_mfma_f32_16x16x32_bf16(ap[ti], bv[tj], Oacc[ti][tj], 0, 0, 0);
      __builtin_amdgcn_s_setprio(0);
    }
  }

#pragma unroll
  for (int ti = 0; ti < 2; ti++)
#pragma unroll
    for (int r = 0; r < 4; r++) {
#pragma unroll
      for (int o = 1; o < 16; o <<= 1) lacc[ti][r] += __shfl_xor(lacc[ti][r], o);
    }
  long pb = ((long)bh * 16 + ns) * 256;
#pragma unroll
  for (int ti = 0; ti < 2; ti++)
#pragma unroll
    for (int r = 0; r < 4; r++) {
      int row = wr0 + ti * 16 + quad * 4 + r;
      if (l16 == 0) lpart[pb + row] = lacc[ti][r];
#pragma unroll
      for (int tj = 0; tj < 4; tj++)
        Opart[(pb + row) * 64 + tj * 16 + l16] = Oacc[ti][tj][r];
    }
}

__global__ __launch_bounds__(256) void f3_combine(const float* __restrict__ Opart,
    const float* __restrict__ lpart, bf16* __restrict__ a3v) {
  int row = blockIdx.x * 4 + (threadIdx.x >> 6);
  int d = threadIdx.x & 63;
  int bh = row >> 8, m = row & 255;
  float so = 0.f, sl = 0.f;
#pragma unroll
  for (int s = 0; s < 16; s++) {
    long pb = ((long)bh * 16 + s) * 256 + m;
    so += Opart[pb * 64 + d];
    sl += lpart[pb];
  }
  a3v[(long)row * 64 + d] = (bf16)(so / sl);
}

// ---------------- F1: fused a1-softmax @ W + Toeplitz-MFMA conv + reorder ----------------
// Round-7 structure, vsT LDS buffer DELETED: conv B-fragments loaded directly from
// global v (imm-offset scalar loads; 4 tj cover full 128B lines -> no over-fetch).
// LDS 48.6K -> 35.1K => 4 blocks/CU; no staging phase, no 8-way-conflicted LDS writes.
__global__ __launch_bounds__(256) void f1_attn(const bf16* __restrict__ q,
    const bf16* __restrict__ kl, const bf16* __restrict__ WT, const bf16* __restrict__ v,
    const float* __restrict__ wconv, bf16* __restrict__ xattn) {
  const int nt = blockIdx.x, bh = blockIdx.y;
  const int h = bh & 7, b = bh >> 3, n0 = nt * 64;
  const int tid = threadIdx.x, lane = tid & 63, wave = tid >> 6;
  const int quad = lane >> 4, l16 = lane & 15;
  __shared__ __align__(16) bf16 Pts[64][264];
  __shared__ float red[4][64];
  __shared__ float linv[64];

  const bf16* qb  = q + (long)bh * 262144;
  const bf16* klb = kl + (long)bh * 16384;
  const bf16* wtb = WT + (long)bh * 16384;
  const bf16* vb  = v + (long)bh * 262144;

  // conv weights held in registers: lane l holds w[l] for l<33
  float wreg = (lane < 33) ? wconv[h * 33 + lane] : 0.f;

  // Phase S: wave covers all 64 rows x its 64 landmark cols
  f32x4 zero = {0.f, 0.f, 0.f, 0.f};
  f32x4 sacc[4][4];
#pragma unroll
  for (int i = 0; i < 4; i++)
#pragma unroll
    for (int j = 0; j < 4; j++) sacc[i][j] = zero;
#pragma unroll
  for (int ki = 0; ki < 2; ki++) {
    bf16x8 aq[4], bk[4];
#pragma unroll
    for (int ti = 0; ti < 4; ti++)
      aq[ti] = *(const bf16x8*)&qb[(long)(n0 + ti * 16 + l16) * 64 + ki * 32 + quad * 8];
#pragma unroll
    for (int tj = 0; tj < 4; tj++)
      bk[tj] = *(const bf16x8*)&klb[(long)(wave * 64 + tj * 16 + l16) * 64 + ki * 32 + quad * 8];
#pragma unroll
    for (int ti = 0; ti < 4; ti++)
#pragma unroll
      for (int tj = 0; tj < 4; tj++)
        sacc[ti][tj] = __builtin_amdgcn_mfma_f32_16x16x32_bf16(aq[ti], bk[tj], sacc[ti][tj], 0, 0, 0);
  }
  float ps[4][4] = {};
#pragma unroll
  for (int ti = 0; ti < 4; ti++)
#pragma unroll
    for (int tj = 0; tj < 4; tj++)
#pragma unroll
      for (int r = 0; r < 4; r++) {
        float e = __expf(sacc[ti][tj][r]);
        ps[ti][r] += e;
        Pts[ti * 16 + quad * 4 + r][wave * 64 + tj * 16 + l16] = (bf16)e;
      }
#pragma unroll
  for (int ti = 0; ti < 4; ti++)
#pragma unroll
    for (int r = 0; r < 4; r++) {
#pragma unroll
      for (int o = 1; o < 16; o <<= 1) ps[ti][r] += __shfl_xor(ps[ti][r], o);
      if (l16 == 0) red[wave][ti * 16 + quad * 4 + r] = ps[ti][r];
    }
  __syncthreads();
  if (tid < 64) linv[tid] = 1.f / (red[0][tid] + red[1][tid] + red[2][tid] + red[3][tid]);
  __syncthreads();

  // Phase PV: wave owns 16 rows; K=256 over P (LDS) x WT (global)
  const int r0 = wave * 16;
  f32x4 Oacc[4];
#pragma unroll
  for (int j = 0; j < 4; j++) Oacc[j] = zero;
#pragma unroll
  for (int ki = 0; ki < 8; ki++) {
    bf16x8 ap = *(const bf16x8*)&Pts[r0 + l16][ki * 32 + quad * 8];
    bf16x8 bw[4];
#pragma unroll
    for (int tj = 0; tj < 4; tj++)
      bw[tj] = *(const bf16x8*)&wtb[(long)(tj * 16 + l16) * 256 + ki * 32 + quad * 8];
#pragma unroll
    for (int tj = 0; tj < 4; tj++)
      Oacc[tj] = __builtin_amdgcn_mfma_f32_16x16x32_bf16(ap, bw[tj], Oacc[tj], 0, 0, 0);
  }

  // Conv via banded-Toeplitz MFMA with DIRECT global v loads:
  // bv[tj][j] = v[n0-16+ki*32+quad*8+j][tj*16+l16] (zero outside [0,4096))
  f32x4 Cacc[4];
#pragma unroll
  for (int j = 0; j < 4; j++) Cacc[j] = zero;
#pragma unroll
  for (int ki = 0; ki < 3; ki++) {
    if (ki * 32 + 31 < r0 || ki * 32 > r0 + 47) continue;   // wave-uniform skip
    bf16x8 av;
#pragma unroll
    for (int j = 0; j < 8; j++) {
      int idx = ki * 32 + quad * 8 + j - r0 - l16;
      float wv = __shfl(wreg, idx & 63);
      av[j] = (idx >= 0 && idx < 33) ? (bf16)wv : (bf16)0.f;
    }
    int nbase = n0 - 16 + ki * 32 + quad * 8;
    bf16x8 bv[4];
#pragma unroll
    for (int tj = 0; tj < 4; tj++) {
      int d = tj * 16 + l16;
#pragma unroll
      for (int j = 0; j < 8; j++) {
        int n = nbase + j;
        int nc = n < 0 ? 0 : (n > 4095 ? 4095 : n);
        bf16 val = vb[(long)nc * 64 + d];
        bv[tj][j] = (n >= 0 && n < 4096) ? val : (bf16)0.f;
      }
    }
#pragma unroll
    for (int tj = 0; tj < 4; tj++)
      Cacc[tj] = __builtin_amdgcn_mfma_f32_16x16x32_bf16(av, bv[tj], Cacc[tj], 0, 0, 0);
  }

  // Epilogue: out = Oacc/l + conv, write [b][n][h*64+d]
#pragma unroll
  for (int rr = 0; rr < 4; rr++) {
    int row = r0 + quad * 4 + rr;
    float inv = linv[row];
    int n = n0 + row;
#pragma unroll
    for (int tj = 0; tj < 4; tj++) {
      int d = tj * 16 + l16;
      xattn[(((long)b * 4096 + n) << 9) + (h << 6) + d] = (bf16)(Oacc[tj][rr] * inv + Cacc[tj][rr]);
    }
  }
}

// ---------------- host ----------------
extern "C" void kernel_launch(void* const* d_in, const int* in_sizes, int n_in,
                              void* d_out, int out_size, void* d_ws, size_t ws_size,
                              hipStream_t stream) {
  (void)in_sizes; (void)n_in; (void)out_size; (void)ws_size;
  const float* x      = (const float*)d_in[0];
  const float* ln_w   = (const float*)d_in[1];
  const float* ln_b   = (const float*)d_in[2];
  const float* w_qkv  = (const float*)d_in[3];
  const float* w_out  = (const float*)d_in[4];
  const float* b_out  = (const float*)d_in[5];
  const float* w_conv = (const float*)d_in[6];
  float* out = (float*)d_out;

  // workspace plan (MB offsets); f3 now uses a 32 MiB Opart overlaying the
  // dead NS region 48..80, with the final z redirected to zfin@80 (consumed by
  // the WT gemm before f1 overwrites 73..89 with xattn).
  char* ws = (char*)d_ws;
  const size_t MB = 1u << 20;
  bf16* q      = (bf16*)(ws + 0 * MB);
  bf16* k      = (bf16*)(ws + 16 * MB);
  bf16* v      = (bf16*)(ws + 32 * MB);
  bf16* xn     = (bf16*)(ws + 48 * MB);
  bf16* a2_h   = (bf16*)(ws + 48 * MB);
  bf16* pbuf   = (bf16*)(ws + 52 * MB);
  bf16* qbuf   = (bf16*)(ws + 56 * MB);
  bf16* rbuf   = (bf16*)(ws + 60 * MB);
  bf16* bufA   = (bf16*)(ws + 64 * MB);
  bf16* bufB   = (bf16*)(ws + 72 * MB);
  float* Opart = (float*)(ws + 48 * MB);   // 32 MiB (48..80), post-NS overlay
  bf16* zfin   = (bf16*)(ws + 80 * MB);    // 4 MB final pinv z
  float* lpart = (float*)(ws + 84 * MB);   // 512 KB
  bf16* xattn  = (bf16*)(ws + 73 * MB);    // written by f1 AFTER WT gemm reads zfin
  bf16* wqkvT  = (bf16*)(ws + 73 * MB);    // dead before f1
  bf16* ql     = (bf16*)(ws + 89 * MB);
  bf16* kl     = (bf16*)(ws + 90 * MB);
  bf16* a3v    = (bf16*)(ws + 91 * MB);
  bf16* WT     = (bf16*)(ws + 93 * MB);
  bf16* woutT  = (bf16*)(ws + 94 * MB);
  float* scal  = (float*)(ws + 94 * MB + 512 * 1024);

  prep_w<<<512, 256, 0, stream>>>(w_qkv, w_out, wqkvT, woutT);
  ln_kernel<<<4096, 256, 0, stream>>>(x, ln_w, ln_b, xn);

  // QKV projection (glds-staged), scatter into [b,h,n,d]
  gemm_g<128, MODE_QKV><<<dim3(128, 12, 1), 256, 0, stream>>>(
      xn, wqkvT, nullptr, 1536, 512, 0, 0, 0, 1.f, 0.f, nullptr, nullptr, q, k, v);

  lm_kernel<<<dim3(32, 64), 256, 0, stream>>>(q, k, ql, kl);

  // a2 = softmax(ql @ kl^T), softmax fused into GEMM epilogue
  a2_kernel<<<dim3(4, 32), 256, 0, stream>>>(ql, kl, a2_h);

  // z0 = a2^T / c (tiled transpose) ; y0 = a2 a2^T / c (+ p0 = 7I - y0)
  init_scal<<<1, 1, 0, stream>>>(scal);
  red_col<<<dim3(32, 4), 64, 0, stream>>>(a2_h, scal);
  z0_k<<<dim3(32, 16), 256, 0, stream>>>(a2_h, scal, bufA);
  gemm_ns<256, MODE_Y0><<<512, 256, 0, stream>>>(
      a2_h, a2_h, nullptr, 256, 65536, 65536, 65536, 1.f, 7.f, scal,
      bufA + 2097152, pbuf);

  // Newton-Schulz x6, all-symmetric BT chain (XCD-swizzled 1-D grids);
  // final z-update writes to zfin (frees bufA/bufB for the Opart overlay).
  bf16* cur = bufA;
  bf16* nxt = bufB;
  for (int it = 0; it < 6; it++) {
    gemm_ns<256, MODE_DIAG><<<512, 256, 0, stream>>>(
        cur + 2097152, pbuf, qbuf, 256, 65536, 65536, 65536, 1.f, 15.f,
        nullptr, nullptr, nullptr);
    gemm_ns<256, MODE_DIAG><<<512, 256, 0, stream>>>(
        cur + 2097152, qbuf, rbuf, 256, 65536, 65536, 65536, 1.f, 13.f,
        nullptr, nullptr, nullptr);
    if (it < 5) {
      gemm_ns<256, MODE_ZY><<<1024, 256, 0, stream>>>(
          cur, rbuf, nxt, 256, 65536, 65536, 65536, 0.25f, 7.f,
          nullptr, nullptr, pbuf);
      bf16* tmp = cur; cur = nxt; nxt = tmp;
    } else {
      gemm_ns<256, MODE_BF16><<<512, 256, 0, stream>>>(
          cur, rbuf, zfin, 256, 65536, 65536, 65536, 0.25f, 0.f,
          nullptr, nullptr, nullptr);
    }
  }

  // fused a3-softmax @ v (16-way n-split)
  f3_partial<<<dim3(2, 16, 32), 256, 0, stream>>>(ql, k, v, Opart, lpart);
  f3_combine<<<2048, 256, 0, stream>>>(Opart, lpart, a3v);

  // WT = (a2inv @ a3v)^T directly via transposed-write epilogue
  gemm_k<64, 64, false, MODE_BF16T><<<dim3(4, 1, 32), 256, 0, stream>>>(
      zfin, a3v, WT, 256, 64, 256, 65536, 16384, 16384, 1.f, 0.f, nullptr, nullptr, nullptr, nullptr, nullptr);

  // fused a1-softmax @ W + conv (direct v loads) + reorder
  f1_attn<<<dim3(64, 32), 256, 0, stream>>>(q, kl, WT, v, w_conv, xattn);

  // out = x + xattn @ w_out + b_out (glds-staged)
  gemm_g<128, MODE_RESID><<<dim3(128, 4, 1), 256, 0, stream>>>(
      xattn, woutT, out, 512, 512, 0, 0, 0, 1.f, 0.f, x, b_out, nullptr, nullptr, nullptr);
}

// Round 12
// 401.237 us; speedup vs baseline: 1.0402x; 1.0402x over previous
//
#include <hip/hip_runtime.h>
#include <cstdint>

typedef __bf16 bf16;
typedef __bf16 bf16x8 __attribute__((ext_vector_type(8)));
typedef float  f32x4  __attribute__((ext_vector_type(4)));

// direct global->LDS 16B copy: LDS dest is wave-uniform base + lane*16B (HW rule),
// global src is per-lane.
__device__ __forceinline__ void glds16(const void* g, void* l) {
  __builtin_amdgcn_global_load_lds((const __attribute__((address_space(1))) void*)g,
                                   (__attribute__((address_space(3))) void*)l, 16, 0, 0);
}

// ---------------- merged weight prep ----------------
__global__ __launch_bounds__(256) void prep_w(const float* __restrict__ wqkv, const float* __restrict__ wout,
                                              bf16* __restrict__ wqkvT, bf16* __restrict__ woutT) {
  int idx = blockIdx.x * 256 + threadIdx.x;
  if (idx < 98304) {
    int r8 = idx & 63, c = idx >> 6;
    bf16 o[8];
#pragma unroll
    for (int e = 0; e < 8; e++) o[e] = (bf16)wqkv[(long)(r8 * 8 + e) * 1536 + c];
    *(uint4*)(wqkvT + (long)c * 512 + r8 * 8) = *(uint4*)o;
  } else {
    int j = idx - 98304;
    int r8 = j & 63, c = j >> 6;
    bf16 o[8];
#pragma unroll
    for (int e = 0; e < 8; e++) o[e] = (bf16)wout[(long)(r8 * 8 + e) * 512 + c];
    *(uint4*)(woutT + (long)c * 512 + r8 * 8) = *(uint4*)o;
  }
}

// ---------------- LayerNorm: 4 rows per block (one wave per row) ----------------
__global__ __launch_bounds__(256) void ln_kernel(const float* __restrict__ x,
    const float* __restrict__ w, const float* __restrict__ b, bf16* __restrict__ xn) {
  long row = (long)blockIdx.x * 4 + (threadIdx.x >> 6);
  int t = threadIdx.x & 63;
  const float* rp = x + row * 512 + t * 8;
  float4 p0 = *(const float4*)rp;
  float4 p1 = *(const float4*)(rp + 4);
  float vals[8] = {p0.x, p0.y, p0.z, p0.w, p1.x, p1.y, p1.z, p1.w};
  float s = 0.f, s2 = 0.f;
#pragma unroll
  for (int e = 0; e < 8; e++) { s += vals[e]; s2 += vals[e] * vals[e]; }
#pragma unroll
  for (int o = 32; o > 0; o >>= 1) { s += __shfl_xor(s, o); s2 += __shfl_xor(s2, o); }
  float mu = s * (1.f / 512.f);
  float var = s2 * (1.f / 512.f) - mu * mu;
  float rstd = rsqrtf(var + 1e-5f);
  float4 w0 = *(const float4*)(w + t * 8), w1 = *(const float4*)(w + t * 8 + 4);
  float4 b0 = *(const float4*)(b + t * 8), b1 = *(const float4*)(b + t * 8 + 4);
  float wv[8] = {w0.x, w0.y, w0.z, w0.w, w1.x, w1.y, w1.z, w1.w};
  float bv[8] = {b0.x, b0.y, b0.z, b0.w, b1.x, b1.y, b1.z, b1.w};
  bf16 outv[8];
#pragma unroll
  for (int e = 0; e < 8; e++) outv[e] = (bf16)((vals[e] - mu) * rstd * wv[e] + bv[e]);
  *(uint4*)(xn + row * 512 + t * 8) = *(uint4*)outv;
}

enum { MODE_BF16 = 1, MODE_QKV = 2, MODE_RESID = 3, MODE_XZ = 4, MODE_DIAG = 5, MODE_Y0 = 6, MODE_ZY = 7, MODE_BF16T = 8 };

// ---------------- full-K LDS 64x64 GEMM for NS chain: C = alpha * A @ B^T ----------------
// 1-D grid with XCD-aware work remap (confirmed r10: -25 us): id%8 == batch%8 so each
// XCD's private L2 serves only 4 batches (2 MB) instead of all 32 (8 MB thrash).
template <int KDIM, int MODE>
__global__ __launch_bounds__(256) void gemm_ns(
    const bf16* __restrict__ A, const bf16* __restrict__ B, void* __restrict__ C,
    int N, long sA, long sB, long sC, float alpha, float cdiag,
    const float* __restrict__ scal, bf16* __restrict__ aux0, bf16* __restrict__ aux1) {
  constexpr int BM = 64;
  __shared__ __align__(16) bf16 As[BM * KDIM];
  __shared__ __align__(16) bf16 Bs[BM * KDIM];
  const int tid = threadIdx.x, lane = tid & 63, wave = tid >> 6;
  const int quad = lane >> 4, l16 = lane & 15;
  constexpr int LPR = KDIM / 8;
  constexpr int CPW = (BM * KDIM / 512) / 4;
  constexpr int RPC = 64 / LPR;
  // XCD-aware decomposition of the 1-D block id
  const int id = blockIdx.x;
  const int xr = id & 7, g = id >> 3;
  const int batch = xr + 8 * (g >> 4);       // batch%8 == id%8
  const int t16 = g & 15;
  const int bm0 = (t16 >> 2) * BM, bn0 = (t16 & 3) * BM;
  const bf16* Ab = A + (long)batch * sA;
  const bf16* Bb = B + (long)(MODE == MODE_ZY ? (batch & 31) : batch) * sB;

  const int rin = lane / LPR, gr = lane % LPR;
#pragma unroll
  for (int t = 0; t < CPW; t++) {
    int seg = wave * CPW + t;
    int row = seg * RPC + rin;
    int scol = 8 * (gr ^ (row & 7));
    glds16(&Ab[(long)(bm0 + row) * KDIM + scol], &As[seg * 512]);
    glds16(&Bb[(long)(bn0 + row) * KDIM + scol], &Bs[seg * 512]);
  }
  __syncthreads();

  f32x4 zero = {0.f, 0.f, 0.f, 0.f};
  f32x4 acc[4];
#pragma unroll
  for (int j = 0; j < 4; j++) acc[j] = zero;
  const int arow = wave * 16 + l16;
  const int aswz = (l16 & 7) * 8;
#pragma unroll
  for (int ki = 0; ki < KDIM / 32; ki++) {
    int cph = (ki * 32 + quad * 8) ^ aswz;
    bf16x8 af = *(const bf16x8*)&As[arow * KDIM + cph];
    bf16x8 bfr[4];
#pragma unroll
    for (int j = 0; j < 4; j++)
      bfr[j] = *(const bf16x8*)&Bs[(j * 16 + l16) * KDIM + cph];
#pragma unroll
    for (int j = 0; j < 4; j++)
      acc[j] = __builtin_amdgcn_mfma_f32_16x16x32_bf16(af, bfr[j], acc[j], 0, 0, 0);
  }

  const long cb = (long)batch * sC;
  float rscale = 1.f;
  if (MODE == MODE_Y0) rscale = 1.f / (scal[0] * scal[1]);
#pragma unroll
  for (int j = 0; j < 4; j++)
#pragma unroll
    for (int r = 0; r < 4; r++) {
      int row = bm0 + wave * 16 + quad * 4 + r;
      int col = bn0 + j * 16 + l16;
      float v = acc[j][r] * alpha;
      if (MODE == MODE_BF16) {
        ((bf16*)C)[cb + (long)row * N + col] = (bf16)v;
      } else if (MODE == MODE_Y0) {
        long o = cb + (long)row * N + col;
        float vv = v * rscale;
        aux0[o] = (bf16)vv;
        aux1[o] = (bf16)(((row == col) ? cdiag : 0.f) - vv);
      } else if (MODE == MODE_ZY) {
        long o = cb + (long)row * N + col;
        ((bf16*)C)[o] = (bf16)v;
        if (batch >= 32) aux1[o - 2097152] = (bf16)(((row == col) ? cdiag : 0.f) - v);
      } else if (MODE == MODE_DIAG) {
        ((bf16*)C)[cb + (long)row * N + col] = (bf16)(((row == col) ? cdiag : 0.f) - v);
      }
    }
}

// ---------------- a2 GEMM with fused row-softmax: a2 = softmax(ql @ kl^T) ----------------
__global__ __launch_bounds__(256) void a2_kernel(const bf16* __restrict__ ql,
    const bf16* __restrict__ kl, bf16* __restrict__ a2h) {
  __shared__ __align__(16) bf16 As[64 * 64];
  __shared__ __align__(16) bf16 Bs[256 * 64];
  const int tid = threadIdx.x, lane = tid & 63, wave = tid >> 6;
  const int quad = lane >> 4, l16 = lane & 15;
  const int bm0 = blockIdx.x * 64, bh = blockIdx.y;
  const bf16* Ab = ql + (long)bh * 16384;
  const bf16* Bb = kl + (long)bh * 16384;

  const int rin = lane >> 3, gr = lane & 7;
#pragma unroll
  for (int t = 0; t < 2; t++) {
    int seg = wave * 2 + t;
    int row = seg * 8 + rin;
    int scol = 8 * (gr ^ (row & 7));
    glds16(&Ab[(long)(bm0 + row) * 64 + scol], &As[seg * 512]);
  }
#pragma unroll
  for (int t = 0; t < 8; t++) {
    int seg = wave * 8 + t;
    int row = seg * 8 + rin;
    int scol = 8 * (gr ^ (row & 7));
    glds16(&Bb[(long)row * 64 + scol], &Bs[seg * 512]);
  }
  __syncthreads();

  f32x4 zero = {0.f, 0.f, 0.f, 0.f};
  f32x4 acc[16];
#pragma unroll
  for (int j = 0; j < 16; j++) acc[j] = zero;
  const int arow = wave * 16 + l16;
  const int aswz = (l16 & 7) * 8;
#pragma unroll
  for (int ki = 0; ki < 2; ki++) {
    int cph = (ki * 32 + quad * 8) ^ aswz;
    bf16x8 af = *(const bf16x8*)&As[arow * 64 + cph];
#pragma unroll
    for (int j = 0; j < 16; j++) {
      bf16x8 bfr = *(const bf16x8*)&Bs[(j * 16 + l16) * 64 + cph];
      acc[j] = __builtin_amdgcn_mfma_f32_16x16x32_bf16(af, bfr, acc[j], 0, 0, 0);
    }
  }

#pragma unroll
  for (int r = 0; r < 4; r++) {
    float vv[16];
    float m = -3.4e38f;
#pragma unroll
    for (int j = 0; j < 16; j++) {
      vv[j] = (float)(bf16)acc[j][r];
      m = fmaxf(m, vv[j]);
    }
#pragma unroll
    for (int o = 1; o < 16; o <<= 1) m = fmaxf(m, __shfl_xor(m, o));
    float s = 0.f;
#pragma unroll
    for (int j = 0; j < 16; j++) { vv[j] = __expf(vv[j] - m); s += vv[j]; }
#pragma unroll
    for (int o = 1; o < 16; o <<= 1) s += __shfl_xor(s, o);
    int row = bm0 + wave * 16 + quad * 4 + r;
    long base = (long)bh * 65536 + (long)row * 256;
#pragma unroll
    for (int j = 0; j < 16; j++)
      a2h[base + j * 16 + l16] = (bf16)(vv[j] / s);
  }
}

// ---------------- BT=true batched MFMA GEMM with glds staging (QKV / RESID) ----------------
template <int BM, int MODE>
__global__ __launch_bounds__(256) void gemm_g(
    const bf16* __restrict__ A, const bf16* __restrict__ B, void* __restrict__ C,
    int N, int K, long sA, long sB, long sC, float alpha, float cdiag,
    const float* __restrict__ resid, const float* __restrict__ bias,
    bf16* __restrict__ aux0, bf16* __restrict__ aux1, bf16* __restrict__ aux2) {
  constexpr int BK = 32, BN = BM;
  __shared__ __align__(16) bf16 As[BM * BK];
  __shared__ __align__(16) bf16 Bs[BN * BK];
  const int tid = threadIdx.x, lane = tid & 63, wave = tid >> 6;
  const int quad = lane >> 4, l16 = lane & 15;
  constexpr int WN = (BN >= 128) ? 2 : 1;
  constexpr int WM = 4 / WN;
  constexpr int TM = BM / (WM * 16), TN = BN / (WN * 16);
  constexpr int ISS = BM / 64;
  const int wm0 = (wave / WN) * (BM / WM);
  const int wn0 = (wave % WN) * (BN / WN);
  const int bm0 = blockIdx.x * BM, bn0 = blockIdx.y * BN;
  const bf16* Ab = A + (long)blockIdx.z * sA;
  const bf16* Bb = B + (long)blockIdx.z * sB;
  const int srow = lane >> 2, scol = (lane & 3) * 8;

  f32x4 zero = {0.f, 0.f, 0.f, 0.f};
  f32x4 acc[TM][TN];
#pragma unroll
  for (int i = 0; i < TM; i++)
#pragma unroll
    for (int j = 0; j < TN; j++) acc[i][j] = zero;

  for (int k0 = 0; k0 < K; k0 += BK) {
#pragma unroll
    for (int t = 0; t < ISS; t++) {
      int seg = wave * ISS + t;
      glds16(&Ab[(long)(bm0 + seg * 16 + srow) * K + k0 + scol], &As[seg * 512]);
      glds16(&Bb[(long)(bn0 + seg * 16 + srow) * K + k0 + scol], &Bs[seg * 512]);
    }
    __syncthreads();
    bf16x8 af[TM], bfr[TN];
#pragma unroll
    for (int i = 0; i < TM; i++)
      af[i] = *(const bf16x8*)&As[(wm0 + i * 16 + l16) * BK + quad * 8];
#pragma unroll
    for (int j = 0; j < TN; j++)
      bfr[j] = *(const bf16x8*)&Bs[(wn0 + j * 16 + l16) * BK + quad * 8];
#pragma unroll
    for (int i = 0; i < TM; i++)
#pragma unroll
      for (int j = 0; j < TN; j++)
        acc[i][j] = __builtin_amdgcn_mfma_f32_16x16x32_bf16(af[i], bfr[j], acc[i][j], 0, 0, 0);
    __syncthreads();
  }

#pragma unroll
  for (int i = 0; i < TM; i++)
#pragma unroll
    for (int j = 0; j < TN; j++)
#pragma unroll
      for (int r = 0; r < 4; r++) {
        int row = bm0 + wm0 + i * 16 + quad * 4 + r;
        int col = bn0 + wn0 + j * 16 + l16;
        float v = acc[i][j][r] * alpha;
        if (MODE == MODE_QKV) {
          int b = row >> 12, n = row & 4095;
          int which = col >> 9, h = (col >> 6) & 7, d = col & 63;
          long o = ((long)(b * 8 + h) * 4096 + n) * 64 + d;
          if (which == 0) aux0[o] = (bf16)(v * 0.125f);
          else if (which == 1) aux1[o] = (bf16)v;
          else aux2[o] = (bf16)v;
        } else {  // MODE_RESID
          long o = (long)row * N + col;
          ((float*)C)[o] = v + bias[col] + resid[o];
        }
      }
}

// ---------------- legacy GEMM (lone BT=false W-gemm, transposed-write epilogue) ----------------
template <int BM, int BN, bool BT, int MODE>
__global__ __launch_bounds__(256) void gemm_k(
    const bf16* __restrict__ A, const bf16* __restrict__ B, void* __restrict__ C,
    int M, int N, int K, long sA, long sB, long sC, float alpha, float cdiag,
    const float* __restrict__ resid, const float* __restrict__ bias,
    bf16* __restrict__ aux0, bf16* __restrict__ aux1, bf16* __restrict__ aux2) {
  constexpr int BK = 32, LDST = 40;
  __shared__ __align__(16) bf16 As[BM * LDST];
  __shared__ __align__(16) bf16 Bs[BN * LDST];
  const int tid = threadIdx.x, lane = tid & 63, wave = tid >> 6;
  const int quad = lane >> 4, l16 = lane & 15;
  constexpr int WN = (BN >= 128) ? 2 : 1;
  constexpr int WM = 4 / WN;
  constexpr int TM = BM / (WM * 16), TN = BN / (WN * 16);
  const int wm0 = (wave / WN) * (BM / WM);
  const int wn0 = (wave % WN) * (BN / WN);
  const int bm0 = blockIdx.x * BM, bn0 = blockIdx.y * BN;
  const bf16* Ab = A + (long)blockIdx.z * sA;
  const bf16* Bb = B + (long)blockIdx.z * sB;

  f32x4 zero = {0.f, 0.f, 0.f, 0.f};
  f32x4 acc[TM][TN];
#pragma unroll
  for (int i = 0; i < TM; i++)
#pragma unroll
    for (int j = 0; j < TN; j++) acc[i][j] = zero;

  for (int k0 = 0; k0 < K; k0 += BK) {
    for (int c = tid; c < BM * 4; c += 256) {
      int r = c >> 2, cv = (c & 3) * 8;
      *(uint4*)&As[r * LDST + cv] = *(const uint4*)&Ab[(long)(bm0 + r) * K + k0 + cv];
    }
    if (BT) {
      for (int c = tid; c < BN * 4; c += 256) {
        int r = c >> 2, cv = (c & 3) * 8;
        *(uint4*)&Bs[r * LDST + cv] = *(const uint4*)&Bb[(long)(bn0 + r) * K + k0 + cv];
      }
    } else {
      for (int c = tid; c < BN * 4; c += 256) {
        int kk = c / (BN / 8), nv = (c % (BN / 8)) * 8;
        uint4 tmp = *(const uint4*)&Bb[(long)(k0 + kk) * N + bn0 + nv];
        const bf16* tv = (const bf16*)&tmp;
#pragma unroll
        for (int e = 0; e < 8; e++) Bs[(nv + e) * LDST + kk] = tv[e];
      }
    }
    __syncthreads();
    bf16x8 af[TM], bfr[TN];
#pragma unroll
    for (int i = 0; i < TM; i++)
      af[i] = *(const bf16x8*)&As[(wm0 + i * 16 + l16) * LDST + quad * 8];
#pragma unroll
    for (int j = 0; j < TN; j++)
      bfr[j] = *(const bf16x8*)&Bs[(wn0 + j * 16 + l16) * LDST + quad * 8];
#pragma unroll
    for (int i = 0; i < TM; i++)
#pragma unroll
      for (int j = 0; j < TN; j++)
        acc[i][j] = __builtin_amdgcn_mfma_f32_16x16x32_bf16(af[i], bfr[j], acc[i][j], 0, 0, 0);
    __syncthreads();
  }

  const long cb = (long)blockIdx.z * sC;
#pragma unroll
  for (int i = 0; i < TM; i++)
#pragma unroll
    for (int j = 0; j < TN; j++)
#pragma unroll
      for (int r = 0; r < 4; r++) {
        int row = bm0 + wm0 + i * 16 + quad * 4 + r;
        int col = bn0 + wn0 + j * 16 + l16;
        float v = acc[i][j][r] * alpha;
        if (MODE == MODE_BF16) {
          ((bf16*)C)[cb + (long)row * N + col] = (bf16)v;
        } else if (MODE == MODE_BF16T) {   // transposed write: C[col][row]
          ((bf16*)C)[cb + (long)col * M + row] = (bf16)v;
        }
      }
}

// ---------------- landmark means ----------------
__global__ __launch_bounds__(256) void lm_kernel(const bf16* __restrict__ q, const bf16* __restrict__ k,
                                                 bf16* __restrict__ ql, bf16* __restrict__ kl) {
  int bh = blockIdx.x, mi = blockIdx.y * 4 + (threadIdx.x >> 6), d = threadIdx.x & 63;
  long base = ((long)bh * 4096 + mi * 16) * 64 + d;
  float sq = 0.f, sk = 0.f;
#pragma unroll
  for (int j = 0; j < 16; j++) { sq += (float)q[base + j * 64]; sk += (float)k[base + j * 64]; }
  long o = ((long)bh * 256 + mi) * 64 + d;
  ql[o] = (bf16)(sq * (1.f / 16.f));
  kl[o] = (bf16)(sk * (1.f / 16.f));
}

// ---------------- pinv scale helpers ----------------
__global__ void init_scal(float* scal) { scal[0] = 1.0f; ((int*)scal)[1] = 0; }

__global__ __launch_bounds__(64) void red_col(const bf16* __restrict__ a2h, float* scal) {
  int bh = blockIdx.x;
  int j = blockIdx.y * 64 + threadIdx.x;
  float s = 0.f;
  const bf16* p = a2h + (long)bh * 65536 + j;
  for (int i = 0; i < 256; i++) s += (float)p[i * 256];
  atomicMax((int*)scal + 1, __float_as_int(s));
}

// z0 = a2^T / c via LDS-tiled 64x64 transpose: coalesced reads AND writes
__global__ __launch_bounds__(256) void z0_k(const bf16* __restrict__ a2h,
                                            const float* __restrict__ scal, bf16* __restrict__ z) {
  int bh = blockIdx.x, ti = blockIdx.y;
  int r0 = (ti >> 2) * 64, c0 = (ti & 3) * 64;
  __shared__ __align__(16) bf16 tile[64][72];
  float inv = 1.f / (scal[0] * scal[1]);
  int tid = threadIdx.x;
  const bf16* src = a2h + (long)bh * 65536;
  bf16* dst = z + (long)bh * 65536;
#pragma unroll
  for (int t = 0; t < 2; t++) {
    int i = tid + t * 256;
    int r = i >> 3, c8 = (i & 7) * 8;
    uint4 pk = *(const uint4*)&src[(long)(r0 + r) * 256 + c0 + c8];
    bf16 tmp[8]; *(uint4*)tmp = pk;
    bf16 sc[8];
#pragma unroll
    for (int e = 0; e < 8; e++) sc[e] = (bf16)((float)tmp[e] * inv);
    *(uint4*)&tile[r][c8] = *(uint4*)sc;
  }
  __syncthreads();
#pragma unroll
  for (int t = 0; t < 2; t++) {
    int i = tid + t * 256;
    int jl = i >> 3, c8 = (i & 7) * 8;
    bf16 o[8];
#pragma unroll
    for (int e = 0; e < 8; e++) o[e] = tile[c8 + e][jl];
    *(uint4*)&dst[(long)(c0 + jl) * 256 + r0 + c8] = *(uint4*)o;
  }
}

// ---------------- F3: fused a3-softmax @ v, n-split partials ----------------
// vT staging XOR-swizzled on 16B granules + setprio MFMA clusters (round-6 win, kept).
__global__ __launch_bounds__(256) void f3_partial(const bf16* __restrict__ ql,
    const bf16* __restrict__ k, const bf16* __restrict__ v,
    float* __restrict__ Opart, float* __restrict__ lpart) {
  const int mt = blockIdx.x, ns = blockIdx.y, bh = blockIdx.z;
  const int tid = threadIdx.x, lane = tid & 63, wave = tid >> 6;
  const int quad = lane >> 4, l16 = lane & 15;
  const int wr0 = mt * 128 + wave * 32;
  __shared__ __align__(16) bf16 vT[64][72];
  __shared__ __align__(16) bf16 Pts[4][32][72];

  const bf16* qlb = ql + (long)bh * 16384;
  const bf16* kb  = k + (long)bh * 262144;
  const bf16* vb  = v + (long)bh * 262144;

  bf16x8 aq[2][2];
#pragma unroll
  for (int ti = 0; ti < 2; ti++)
#pragma unroll
    for (int ki = 0; ki < 2; ki++)
      aq[ti][ki] = *(const bf16x8*)&qlb[(wr0 + ti * 16 + l16) * 64 + ki * 32 + quad * 8];

  f32x4 zero = {0.f, 0.f, 0.f, 0.f};
  f32x4 Oacc[2][4];
#pragma unroll
  for (int i = 0; i < 2; i++)
#pragma unroll
    for (int j = 0; j < 4; j++) Oacc[i][j] = zero;
  float lacc[2][4] = {};

  for (int c = 0; c < 8; c++) {
    int n0c = ns * 512 + c * 64;
    __syncthreads();
    for (int i = tid; i < 512; i += 256) {
      int nn = i >> 3, d8 = (i & 7) * 8;
      uint4 pk = *(const uint4*)&vb[(long)(n0c + nn) * 64 + d8];
      const bf16* pv = (const bf16*)&pk;
      int cs = (((nn >> 3) ^ (d8 >> 3)) * 8) + (nn & 7);   // granule-XOR swizzle
#pragma unroll
      for (int e = 0; e < 8; e++) vT[d8 + e][cs] = pv[e];
    }
    __syncthreads();

    f32x4 sacc[2][4];
#pragma unroll
    for (int i = 0; i < 2; i++)
#pragma unroll
      for (int j = 0; j < 4; j++) sacc[i][j] = zero;
#pragma unroll
    for (int ki = 0; ki < 2; ki++) {
      bf16x8 bk[4];
#pragma unroll
      for (int tj = 0; tj < 4; tj++)
        bk[tj] = *(const bf16x8*)&kb[(long)(n0c + tj * 16 + l16) * 64 + ki * 32 + quad * 8];
      __builtin_amdgcn_s_setprio(1);
#pragma unroll
      for (int ti = 0; ti < 2; ti++)
#pragma unroll
        for (int tj = 0; tj < 4; tj++)
          sacc[ti][tj] = __builtin_amdgcn_mfma_f32_16x16x32_bf16(aq[ti][ki], bk[tj], sacc[ti][tj], 0, 0, 0);
      __builtin_amdgcn_s_setprio(0);
    }
#pragma unroll
    for (int ti = 0; ti < 2; ti++)
#pragma unroll
      for (int tj = 0; tj < 4; tj++)
#pragma unroll
        for (int r = 0; r < 4; r++) {
          float e = __expf(sacc[ti][tj][r]);
          lacc[ti][r] += e;
          Pts[wave][ti * 16 + quad * 4 + r][tj * 16 + l16] = (bf16)e;
        }
#pragma unroll
    for (int ki = 0; ki < 2; ki++) {
      bf16x8 ap[2], bv[4];
#pragma unroll
      for (int ti = 0; ti < 2; ti++)
        ap[ti] = *(const bf16x8*)&Pts[wave][ti * 16 + l16][ki * 32 + quad * 8];
#pragma unroll
      for (int tj = 0; tj < 4; tj++) {
        int g = (ki * 4 + quad) ^ ((tj * 2 + (l16 >> 3)) & 7);
        bv[tj] = *(const bf16x8*)&vT[tj * 16 + l16][g * 8];
      }
      __builtin_amdgcn_s_setprio(1);
#pragma unroll
      for (int ti = 0; ti < 2; ti++)
#pragma unroll
        for (int tj = 0; tj < 4; tj++)
          Oacc[ti][tj] = __builtin_amdgcn_mfma_f32_16x16x32_bf16(ap[ti], bv[tj], Oacc[ti][tj], 0, 0, 0);
      __builtin_amdgcn_s_setprio(0);
    }
  }

#pragma unroll
  for (int ti = 0; ti < 2; ti++)
#pragma unroll
    for (int r = 0; r < 4; r++) {
#pragma unroll
      for (int o = 1; o < 16; o <<= 1) lacc[ti][r] += __shfl_xor(lacc[ti][r], o);
    }
  long pb = ((long)bh * 8 + ns) * 256;
#pragma unroll
  for (int ti = 0; ti < 2; ti++)
#pragma unroll
    for (int r = 0; r < 4; r++) {
      int row = wr0 + ti * 16 + quad * 4 + r;
      if (l16 == 0) lpart[pb + row] = lacc[ti][r];
#pragma unroll
      for (int tj = 0; tj < 4; tj++)
        Opart[(pb + row) * 64 + tj * 16 + l16] = Oacc[ti][tj][r];
    }
}

__global__ __launch_bounds__(256) void f3_combine(const float* __restrict__ Opart,
    const float* __restrict__ lpart, bf16* __restrict__ a3v) {
  int row = blockIdx.x * 4 + (threadIdx.x >> 6);
  int d = threadIdx.x & 63;
  int bh = row >> 8, m = row & 255;
  float so = 0.f, sl = 0.f;
#pragma unroll
  for (int s = 0; s < 8; s++) {
    long pb = ((long)bh * 8 + s) * 256 + m;
    so += Opart[pb * 64 + d];
    sl += lpart[pb];
  }
  a3v[(long)row * 64 + d] = (bf16)(so / sl);
}

// ---------------- F1: fused a1-softmax @ W + Toeplitz-MFMA conv + reorder ----------------
// Round-7 best-measured version (62.0 us, VGPR 80): linear vsT staging hidden under S,
// no setprio (barrier-synced lockstep), no prefetch. 10 variants tried; this is the floor.
__global__ __launch_bounds__(256) void f1_attn(const bf16* __restrict__ q,
    const bf16* __restrict__ kl, const bf16* __restrict__ WT, const bf16* __restrict__ v,
    const float* __restrict__ wconv, bf16* __restrict__ xattn) {
  const int nt = blockIdx.x, bh = blockIdx.y;
  const int h = bh & 7, b = bh >> 3, n0 = nt * 64;
  const int tid = threadIdx.x, lane = tid & 63, wave = tid >> 6;
  const int quad = lane >> 4, l16 = lane & 15;
  __shared__ __align__(16) bf16 Pts[64][264];
  __shared__ __align__(16) bf16 vsT[64][104];  // [d][r], r = n - n0 + 16 in [0,96)
  __shared__ float red[4][64];
  __shared__ float linv[64];

  const bf16* qb  = q + (long)bh * 262144;
  const bf16* klb = kl + (long)bh * 16384;
  const bf16* wtb = WT + (long)bh * 16384;
  const bf16* vb  = v + (long)bh * 262144;

  // conv weights held in registers: lane l holds w[l] for l<33
  float wreg = (lane < 33) ? wconv[h * 33 + lane] : 0.f;

  // stage v slice transposed: vsT[d][r] = v[n0-16+r][d] (zero outside [0,4096))
  for (int i = tid; i < 768; i += 256) {
    int r = i >> 3, d8 = (i & 7) * 8;
    int n = n0 - 16 + r;
    uint4 val = {0u, 0u, 0u, 0u};
    if (n >= 0 && n < 4096) val = *(const uint4*)&vb[(long)n * 64 + d8];
    const bf16* pv = (const bf16*)&val;
#pragma unroll
    for (int e = 0; e < 8; e++) vsT[d8 + e][r] = pv[e];
  }

  // Phase S: wave covers all 64 rows x its 64 landmark cols
  f32x4 zero = {0.f, 0.f, 0.f, 0.f};
  f32x4 sacc[4][4];
#pragma unroll
  for (int i = 0; i < 4; i++)
#pragma unroll
    for (int j = 0; j < 4; j++) sacc[i][j] = zero;
#pragma unroll
  for (int ki = 0; ki < 2; ki++) {
    bf16x8 aq[4], bk[4];
#pragma unroll
    for (int ti = 0; ti < 4; ti++)
      aq[ti] = *(const bf16x8*)&qb[(long)(n0 + ti * 16 + l16) * 64 + ki * 32 + quad * 8];
#pragma unroll
    for (int tj = 0; tj < 4; tj++)
      bk[tj] = *(const bf16x8*)&klb[(long)(wave * 64 + tj * 16 + l16) * 64 + ki * 32 + quad * 8];
#pragma unroll
    for (int ti = 0; ti < 4; ti++)
#pragma unroll
      for (int tj = 0; tj < 4; tj++)
        sacc[ti][tj] = __builtin_amdgcn_mfma_f32_16x16x32_bf16(aq[ti], bk[tj], sacc[ti][tj], 0, 0, 0);
  }
  float ps[4][4] = {};
#pragma unroll
  for (int ti = 0; ti < 4; ti++)
#pragma unroll
    for (int tj = 0; tj < 4; tj++)
#pragma unroll
      for (int r = 0; r < 4; r++) {
        float e = __expf(sacc[ti][tj][r]);
        ps[ti][r] += e;
        Pts[ti * 16 + quad * 4 + r][wave * 64 + tj * 16 + l16] = (bf16)e;
      }
#pragma unroll
  for (int ti = 0; ti < 4; ti++)
#pragma unroll
    for (int r = 0; r < 4; r++) {
#pragma unroll
      for (int o = 1; o < 16; o <<= 1) ps[ti][r] += __shfl_xor(ps[ti][r], o);
      if (l16 == 0) red[wave][ti * 16 + quad * 4 + r] = ps[ti][r];
    }
  __syncthreads();
  if (tid < 64) linv[tid] = 1.f / (red[0][tid] + red[1][tid] + red[2][tid] + red[3][tid]);
  __syncthreads();

  // Phase PV: wave owns 16 rows; K=256 over P (LDS) x WT (global)
  const int r0 = wave * 16;
  f32x4 Oacc[4];
#pragma unroll
  for (int j = 0; j < 4; j++) Oacc[j] = zero;
#pragma unroll
  for (int ki = 0; ki < 8; ki++) {
    bf16x8 ap = *(const bf16x8*)&Pts[r0 + l16][ki * 32 + quad * 8];
    bf16x8 bw[4];
#pragma unroll
    for (int tj = 0; tj < 4; tj++)
      bw[tj] = *(const bf16x8*)&wtb[(long)(tj * 16 + l16) * 256 + ki * 32 + quad * 8];
#pragma unroll
    for (int tj = 0; tj < 4; tj++)
      Oacc[tj] = __builtin_amdgcn_mfma_f32_16x16x32_bf16(ap, bw[tj], Oacc[tj], 0, 0, 0);
  }

  // Conv via banded-Toeplitz MFMA: out[m][d] = sum_j w[j-m] * vsT[d][j]
  f32x4 Cacc[4];
#pragma unroll
  for (int j = 0; j < 4; j++) Cacc[j] = zero;
#pragma unroll
  for (int ki = 0; ki < 3; ki++) {
    if (ki * 32 + 31 < r0 || ki * 32 > r0 + 47) continue;   // wave-uniform skip
    bf16x8 av;
#pragma unroll
    for (int j = 0; j < 8; j++) {
      int idx = ki * 32 + quad * 8 + j - r0 - l16;
      float wv = __shfl(wreg, idx & 63);
      av[j] = (idx >= 0 && idx < 33) ? (bf16)wv : (bf16)0.f;
    }
    bf16x8 bv[4];
#pragma unroll
    for (int tj = 0; tj < 4; tj++)
      bv[tj] = *(const bf16x8*)&vsT[tj * 16 + l16][ki * 32 + quad * 8];
#pragma unroll
    for (int tj = 0; tj < 4; tj++)
      Cacc[tj] = __builtin_amdgcn_mfma_f32_16x16x32_bf16(av, bv[tj], Cacc[tj], 0, 0, 0);
  }

  // Epilogue: out = Oacc/l + conv, write [b][n][h*64+d]
#pragma unroll
  for (int rr = 0; rr < 4; rr++) {
    int row = r0 + quad * 4 + rr;
    float inv = linv[row];
    int n = n0 + row;
#pragma unroll
    for (int tj = 0; tj < 4; tj++) {
      int d = tj * 16 + l16;
      xattn[(((long)b * 4096 + n) << 9) + (h << 6) + d] = (bf16)(Oacc[tj][rr] * inv + Cacc[tj][rr]);
    }
  }
}

// ---------------- host ----------------
extern "C" void kernel_launch(void* const* d_in, const int* in_sizes, int n_in,
                              void* d_out, int out_size, void* d_ws, size_t ws_size,
                              hipStream_t stream) {
  (void)in_sizes; (void)n_in; (void)out_size; (void)ws_size;
  const float* x      = (const float*)d_in[0];
  const float* ln_w   = (const float*)d_in[1];
  const float* ln_b   = (const float*)d_in[2];
  const float* w_qkv  = (const float*)d_in[3];
  const float* w_out  = (const float*)d_in[4];
  const float* b_out  = (const float*)d_in[5];
  const float* w_conv = (const float*)d_in[6];
  float* out = (float*)d_out;

  char* ws = (char*)d_ws;
  const size_t MB = 1u << 20;
  bf16* q      = (bf16*)(ws + 0 * MB);
  bf16* k      = (bf16*)(ws + 16 * MB);
  bf16* v      = (bf16*)(ws + 32 * MB);
  bf16* xn     = (bf16*)(ws + 48 * MB);
  bf16* a2_h   = (bf16*)(ws + 48 * MB);
  bf16* pbuf   = (bf16*)(ws + 52 * MB);
  bf16* qbuf   = (bf16*)(ws + 56 * MB);
  bf16* rbuf   = (bf16*)(ws + 60 * MB);
  bf16* bufA   = (bf16*)(ws + 64 * MB);
  bf16* bufB   = (bf16*)(ws + 72 * MB);
  float* Opart = (float*)(ws + 48 * MB);
  float* lpart = (float*)(ws + 72 * MB);
  bf16* xattn  = (bf16*)(ws + 73 * MB);
  bf16* wqkvT  = (bf16*)(ws + 73 * MB);
  bf16* ql     = (bf16*)(ws + 89 * MB);
  bf16* kl     = (bf16*)(ws + 90 * MB);
  bf16* a3v    = (bf16*)(ws + 91 * MB);
  bf16* WT     = (bf16*)(ws + 93 * MB);
  bf16* woutT  = (bf16*)(ws + 94 * MB);
  float* scal  = (float*)(ws + 94 * MB + 512 * 1024);

  prep_w<<<512, 256, 0, stream>>>(w_qkv, w_out, wqkvT, woutT);
  ln_kernel<<<4096, 256, 0, stream>>>(x, ln_w, ln_b, xn);

  // QKV projection (glds-staged), scatter into [b,h,n,d]
  gemm_g<128, MODE_QKV><<<dim3(128, 12, 1), 256, 0, stream>>>(
      xn, wqkvT, nullptr, 1536, 512, 0, 0, 0, 1.f, 0.f, nullptr, nullptr, q, k, v);

  lm_kernel<<<dim3(32, 64), 256, 0, stream>>>(q, k, ql, kl);

  // a2 = softmax(ql @ kl^T), softmax fused into GEMM epilogue
  a2_kernel<<<dim3(4, 32), 256, 0, stream>>>(ql, kl, a2_h);

  // z0 = a2^T / c (tiled transpose) ; y0 = a2 a2^T / c (+ p0 = 7I - y0)
  init_scal<<<1, 1, 0, stream>>>(scal);
  red_col<<<dim3(32, 4), 64, 0, stream>>>(a2_h, scal);
  z0_k<<<dim3(32, 16), 256, 0, stream>>>(a2_h, scal, bufA);
  gemm_ns<256, MODE_Y0><<<512, 256, 0, stream>>>(
      a2_h, a2_h, nullptr, 256, 65536, 65536, 65536, 1.f, 7.f, scal,
      bufA + 2097152, pbuf);

  // Newton-Schulz x6, all-symmetric BT chain (XCD-swizzled 1-D grids)
  bf16* cur = bufA;
  bf16* nxt = bufB;
  for (int it = 0; it < 6; it++) {
    gemm_ns<256, MODE_DIAG><<<512, 256, 0, stream>>>(
        cur + 2097152, pbuf, qbuf, 256, 65536, 65536, 65536, 1.f, 15.f,
        nullptr, nullptr, nullptr);
    gemm_ns<256, MODE_DIAG><<<512, 256, 0, stream>>>(
        cur + 2097152, qbuf, rbuf, 256, 65536, 65536, 65536, 1.f, 13.f,
        nullptr, nullptr, nullptr);
    if (it < 5) {
      gemm_ns<256, MODE_ZY><<<1024, 256, 0, stream>>>(
          cur, rbuf, nxt, 256, 65536, 65536, 65536, 0.25f, 7.f,
          nullptr, nullptr, pbuf);
    } else {
      gemm_ns<256, MODE_BF16><<<512, 256, 0, stream>>>(
          cur, rbuf, nxt, 256, 65536, 65536, 65536, 0.25f, 0.f,
          nullptr, nullptr, nullptr);
    }
    bf16* tmp = cur; cur = nxt; nxt = tmp;
  }

  // fused a3-softmax @ v
  f3_partial<<<dim3(2, 8, 32), 256, 0, stream>>>(ql, k, v, Opart, lpart);
  f3_combine<<<2048, 256, 0, stream>>>(Opart, lpart, a3v);

  // WT = (a2inv @ a3v)^T directly via transposed-write epilogue
  gemm_k<64, 64, false, MODE_BF16T><<<dim3(4, 1, 32), 256, 0, stream>>>(
      cur, a3v, WT, 256, 64, 256, 65536, 16384, 16384, 1.f, 0.f, nullptr, nullptr, nullptr, nullptr, nullptr);

  // fused a1-softmax @ W + conv + reorder
  f1_attn<<<dim3(64, 32), 256, 0, stream>>>(q, kl, WT, v, w_conv, xattn);

  // out = x + xattn @ w_out + b_out (glds-staged)
  gemm_g<128, MODE_RESID><<<dim3(128, 4, 1), 256, 0, stream>>>(
      xattn, woutT, out, 512, 512, 0, 0, 0, 1.f, 0.f, x, b_out, nullptr, nullptr, nullptr);
}